// Round 8
// baseline (158.353 us; speedup 1.0000x reference)
//
#include <hip/hip_runtime.h>
#include <hip/hip_fp16.h>

#define OC 128
#define V_SZ 30000
#define KW 5
#define L_IN 2560              // 40*64
#define L_OUT (L_IN - KW + 1)  // 2556
#define NB 32
#define TCO 4
#define K_ROW (V_SZ * KW)      // 150000 floats per oc row
#define NI (V_SZ * KW)         // i = v*5+w index space
#define TI 128                 // transpose i-tile
#define NTB ((NI + TI - 1) / TI)   // 1172 transpose blocks
#define LDS_S 132              // halfs per i-row in transpose LDS (264B, pad)
#define LTILE 32               // conv l-tile
#define NT 80                  // conv tiles (ceil(2556/32))

// ---------------------------------------------------------------------------
// Kernel A: transpose + fp16-convert  K[oc][i] (f32) -> Kth[i][oc] (f16).
// RETILED: 128 i x 128 oc per block. Global reads are 512B contiguous bursts
// per oc-row (vs 192B before) -> fewer DRAM page activations. Write-out is
// wave-contiguous 512B. fp16 LDS tile (33KB).
// ---------------------------------------------------------------------------
__global__ __launch_bounds__(256) void transpose_k(const float* __restrict__ K,
                                                   __half* __restrict__ Kth) {
    __shared__ __half lds_h[TI * LDS_S];
    const int i0  = blockIdx.x * TI;
    const int tid = threadIdx.x;

    // Read phase: 16 iters; wave = 2 oc-rows x 512B contiguous float4s.
    {
        const int i4  = (tid & 31) * 4;   // 0..124
        const int ocr = tid >> 5;         // 0..7
        #pragma unroll
        for (int p = 0; p < 16; ++p) {
            const int oc = p * 8 + ocr;
            const size_t base = (size_t)oc * K_ROW + i0 + i4;
            float4 kv;
            if (i0 + i4 + 3 < NI) {
                kv = *reinterpret_cast<const float4*>(&K[base]);
            } else {
                kv.x = (i0 + i4 + 0 < NI) ? K[base + 0] : 0.f;
                kv.y = (i0 + i4 + 1 < NI) ? K[base + 1] : 0.f;
                kv.z = (i0 + i4 + 2 < NI) ? K[base + 2] : 0.f;
                kv.w = (i0 + i4 + 3 < NI) ? K[base + 3] : 0.f;
            }
            lds_h[(i4 + 0) * LDS_S + oc] = __float2half(kv.x);
            lds_h[(i4 + 1) * LDS_S + oc] = __float2half(kv.y);
            lds_h[(i4 + 2) * LDS_S + oc] = __float2half(kv.z);
            lds_h[(i4 + 3) * LDS_S + oc] = __float2half(kv.w);
        }
    }
    __syncthreads();

    // Write phase: 16 iters; lane = b64 (4 halfs); wave = 512B contiguous.
    {
        const int oc4 = (tid & 31) * 4;   // 0..124
        const int il0 = tid >> 5;         // 0..7
        #pragma unroll
        for (int c = 0; c < 16; ++c) {
            const int i_loc = c * 8 + il0;
            const int i = i0 + i_loc;
            if (i < NI) {
                const float2 v = *reinterpret_cast<const float2*>(
                    &lds_h[i_loc * LDS_S + oc4]);
                *reinterpret_cast<float2*>(&Kth[(size_t)i * OC + oc4]) = v;
            }
        }
    }
}

// ---------------------------------------------------------------------------
// Kernel B: conv + relu + max-pool from fp16 Kth.
// Grid: (NT=80 l-tiles of 32, 32 b) = 2560 blocks (R6's TLP) with R7's
// partial-write epilogue (no atomics, no memset).
// ---------------------------------------------------------------------------
__global__ __launch_bounds__(256) void conv_max(const int* __restrict__ tokens,
                                                const __half* __restrict__ Kth,
                                                float* __restrict__ partial) {
    __shared__ int   ids[LTILE + KW - 1];   // 36
    __shared__ float red[16 * 128];
    const int b   = blockIdx.y;
    const int l0  = blockIdx.x * LTILE;
    const int tid = threadIdx.x;

    if (tid < LTILE + KW - 1) {
        const int l = l0 + tid;
        ids[tid] = (l < L_IN) ? tokens[b * L_IN + l] : 0;
    }
    __syncthreads();

    const int lgrp = tid >> 4;        // 0..15
    const int oc8  = (tid & 15) * 8;  // 0..120

    float acc[8];
    #pragma unroll
    for (int k = 0; k < 8; ++k) acc[k] = 0.f;

    #pragma unroll
    for (int u = 0; u < 2; ++u) {
        const int li = u * 16 + lgrp;     // 0..31
        const int l  = l0 + li;
        if (l < L_OUT) {
            float s[8];
            #pragma unroll
            for (int k = 0; k < 8; ++k) s[k] = 0.f;
            #pragma unroll
            for (int w = 0; w < KW; ++w) {
                const int id = ids[li + w];
                const float4 raw = *reinterpret_cast<const float4*>(
                    &Kth[((size_t)id * KW + w) * OC + oc8]);
                const __half* h = reinterpret_cast<const __half*>(&raw);
                #pragma unroll
                for (int k = 0; k < 8; ++k) s[k] += __half2float(h[k]);
            }
            #pragma unroll
            for (int k = 0; k < 8; ++k) acc[k] = fmaxf(acc[k], s[k]);
        }
    }

    #pragma unroll
    for (int k = 0; k < 8; ++k) red[lgrp * 128 + oc8 + k] = acc[k];
    __syncthreads();

    if (tid < 128) {
        float m = red[tid];
        #pragma unroll
        for (int g = 1; g < 16; ++g) m = fmaxf(m, red[g * 128 + tid]);
        partial[((size_t)b * NT + blockIdx.x) * OC + tid] = m;  // all slots written
    }
}

// ---------------------------------------------------------------------------
// Kernel C: reduce partials -> pooled, then FC head. Grid 32 x 128 threads.
// ---------------------------------------------------------------------------
__global__ __launch_bounds__(128) void head(const float* __restrict__ partial,
                                            const float* __restrict__ fc1w,
                                            const float* __restrict__ fc1b,
                                            float* __restrict__ out) {
    __shared__ float pooled[OC];
    const int b  = blockIdx.x;
    const int oc = threadIdx.x;

    float m = 0.f;
    #pragma unroll 8
    for (int t = 0; t < NT; ++t)
        m = fmaxf(m, partial[((size_t)b * NT + t) * OC + oc]);
    pooled[oc] = m;
    __syncthreads();

    if (oc < TCO) {
        float acc = fc1b[oc];
        #pragma unroll 4
        for (int c = 0; c < OC; ++c)
            acc += pooled[c] * fc1w[oc * OC + c];
        out[b * TCO + oc] = acc;
    }
}

// ---------------------------------------------------------------------------
// Fallback (ws too small): gather from original f32 layout, atomics path.
// ---------------------------------------------------------------------------
__global__ __launch_bounds__(256) void conv_max_fallback(const int* __restrict__ tokens,
                                                         const float* __restrict__ K,
                                                         int* __restrict__ pooled) {
    const int b   = blockIdx.y;
    const int l0  = blockIdx.x * 64;
    const int tid = threadIdx.x;

    __shared__ int ids[64 + KW - 1];
    if (tid < 64 + KW - 1) {
        const int l = l0 + tid;
        ids[tid] = (l < L_IN) ? tokens[b * L_IN + l] : 0;
    }
    __syncthreads();

    const int oc   = tid & 127;
    const int half = tid >> 7;
    float m = 0.f;
    for (int u = 0; u < 32; ++u) {
        const int li = u * 2 + half;
        const int l  = l0 + li;
        if (l < L_OUT) {
            float s = 0.f;
            #pragma unroll
            for (int w = 0; w < KW; ++w)
                s += K[(size_t)oc * K_ROW + ids[li + w] * KW + w];
            m = fmaxf(m, s);
        }
    }
    atomicMax(&pooled[b * OC + oc], __float_as_int(m));
}

__global__ __launch_bounds__(128) void head_fallback(const int* __restrict__ pooled,
                                                     const float* __restrict__ fc1w,
                                                     const float* __restrict__ fc1b,
                                                     float* __restrict__ out) {
    const int tid = threadIdx.x;
    const int b = tid >> 2;
    const int t = tid & 3;
    float acc = fc1b[t];
    #pragma unroll 4
    for (int oc = 0; oc < OC; ++oc)
        acc += __int_as_float(pooled[b * OC + oc]) * fc1w[t * OC + oc];
    out[b * TCO + t] = acc;
}

extern "C" void kernel_launch(void* const* d_in, const int* in_sizes, int n_in,
                              void* d_out, int out_size, void* d_ws, size_t ws_size,
                              hipStream_t stream) {
    const int*   tokens = (const int*)d_in[0];
    const float* K      = (const float*)d_in[1];
    const float* fc1w   = (const float*)d_in[2];
    const float* fc1b   = (const float*)d_in[3];
    float*       out    = (float*)d_out;

    const size_t kthBytes     = (size_t)NI * OC * sizeof(__half);       // 38.4 MB
    const size_t partialBytes = (size_t)NB * NT * OC * sizeof(float);   // 1.3 MB

    if (ws_size >= kthBytes + partialBytes) {
        __half* Kth    = (__half*)d_ws;
        float* partial = (float*)((char*)d_ws + kthBytes);
        transpose_k<<<NTB, 256, 0, stream>>>(K, Kth);                    // 1172 blocks
        conv_max<<<dim3(NT, NB), 256, 0, stream>>>(tokens, Kth, partial); // 2560 blocks
        head<<<NB, 128, 0, stream>>>(partial, fc1w, fc1b, out);
    } else {
        int* pooled = (int*)d_ws;
        hipMemsetAsync(pooled, 0, (size_t)NB * OC * sizeof(int), stream);
        conv_max_fallback<<<dim3((L_OUT + 63) / 64, NB), 256, 0, stream>>>(tokens, K, pooled);
        head_fallback<<<1, 128, 0, stream>>>(pooled, fc1w, fc1b, out);
    }
}

// Round 12
// 148.202 us; speedup vs baseline: 1.0685x; 1.0685x over previous
//
#include <hip/hip_runtime.h>
#include <hip/hip_fp16.h>

#define OC 128
#define V_SZ 30000
#define KW 5
#define L_IN 2560              // 40*64
#define L_OUT (L_IN - KW + 1)  // 2556
#define NB 32
#define TCO 4
#define K_ROW (V_SZ * KW)      // 150000 floats per oc row
#define NI (V_SZ * KW)         // i = v*5+w index space
#define LTILE 32               // conv l-tile
#define NT ((L_OUT + LTILE - 1) / LTILE)   // 80 conv tiles
#define NPOS (LTILE + KW - 1)  // 36 staged input positions per tile
#define PSTRIDE 656            // halfs per staged position (1312B; 328 words, %32==8 -> bank-balanced)

// ---------------------------------------------------------------------------
// Kernel A: transpose + fp16-convert  K[oc][i] (f32) -> Kth[i][oc] (f16).
// R6-EXACT (best measured). Tile: 48 i x 128 oc, 3125 blocks.
// ---------------------------------------------------------------------------
__global__ __launch_bounds__(256) void transpose_k(const float* __restrict__ K,
                                                   __half* __restrict__ Kth) {
    __shared__ float lds[48 * 132];
    const int i0  = blockIdx.x * 48;
    const int tid = threadIdx.x;

    {
        const int ii4 = (tid & 3) * 4;
        const int ocr = tid >> 2;   // 0..63
        #pragma unroll
        for (int p = 0; p < 3; ++p) {
            #pragma unroll
            for (int r = 0; r < 2; ++r) {
                const int oc = r * 64 + ocr;
                const int ii = p * 16 + ii4;
                const float4 kv = *reinterpret_cast<const float4*>(
                    &K[(size_t)oc * K_ROW + i0 + ii]);
                lds[(ii + 0) * 132 + oc] = kv.x;
                lds[(ii + 1) * 132 + oc] = kv.y;
                lds[(ii + 2) * 132 + oc] = kv.z;
                lds[(ii + 3) * 132 + oc] = kv.w;
            }
        }
    }
    __syncthreads();
    {
        const int oc8 = (tid & 15) * 8;
        #pragma unroll
        for (int p = 0; p < 3; ++p) {
            const int i_loc = p * 16 + (tid >> 4);
            __half h[8];
            #pragma unroll
            for (int k = 0; k < 8; ++k) h[k] = __float2half(lds[i_loc * 132 + oc8 + k]);
            *reinterpret_cast<float4*>(&Kth[(size_t)(i0 + i_loc) * OC + oc8]) =
                *reinterpret_cast<const float4*>(h);
        }
    }
}

// ---------------------------------------------------------------------------
// Kernel B: conv + relu + max-pool from fp16 Kth — PER-POSITION LDS STAGING.
// Grid (NT=80, NB=32) = 2560 blocks, 256 threads.
// Stage: 36 positions x 1280B (= the full 5w x 128oc block of each token id,
// contiguous in Kth) -> 46KB LDS as ~dense sequential wave loads.
// Compute: per (l, w) read half8 from LDS, f32 accumulate, relu-max.
// Epilogue: R6-exact (LDS reduce -> 128 atomicMax).
// ---------------------------------------------------------------------------
__global__ __launch_bounds__(256) void conv_max(const int* __restrict__ tokens,
                                                const __half* __restrict__ Kth,
                                                int* __restrict__ pooled) {
    __shared__ int ids[NPOS];
    __shared__ __align__(16) char smem[NPOS * PSTRIDE * 2];   // 47.2KB
    __half* sk  = reinterpret_cast<__half*>(smem);
    float*  red = reinterpret_cast<float*>(smem);             // aliased after compute

    const int b   = blockIdx.y;
    const int l0  = blockIdx.x * LTILE;
    const int tid = threadIdx.x;

    if (tid < NPOS) {
        const int p = l0 + tid;
        ids[tid] = (p < L_IN) ? tokens[b * L_IN + p] : 0;
    }
    __syncthreads();

    // Stage 36 x 640 halfs. float4 = 8 halfs; 80 float4 per position; 2880 total.
    #pragma unroll
    for (int it = 0; it < 12; ++it) {
        const int q = it * 256 + tid;
        if (q < NPOS * 80) {
            const int p_loc = q / 80;
            const int j     = q - p_loc * 80;       // float4 index in position
            const float4 v = *reinterpret_cast<const float4*>(
                &Kth[(size_t)ids[p_loc] * (KW * OC) + j * 8]);
            *reinterpret_cast<float4*>(&sk[p_loc * PSTRIDE + j * 8]) = v;
        }
    }
    __syncthreads();

    const int lgrp = tid >> 4;        // 0..15
    const int oc8  = (tid & 15) * 8;  // 0..120

    float acc[8];
    #pragma unroll
    for (int k = 0; k < 8; ++k) acc[k] = 0.f;

    #pragma unroll
    for (int u = 0; u < 2; ++u) {
        const int li = u * 16 + lgrp;     // 0..31
        const int l  = l0 + li;
        if (l < L_OUT) {
            float s[8];
            #pragma unroll
            for (int k = 0; k < 8; ++k) s[k] = 0.f;
            #pragma unroll
            for (int w = 0; w < KW; ++w) {
                const float4 raw = *reinterpret_cast<const float4*>(
                    &sk[(li + w) * PSTRIDE + w * OC + oc8]);
                const __half* h = reinterpret_cast<const __half*>(&raw);
                #pragma unroll
                for (int k = 0; k < 8; ++k) s[k] += __half2float(h[k]);
            }
            #pragma unroll
            for (int k = 0; k < 8; ++k) acc[k] = fmaxf(acc[k], s[k]);
        }
    }

    __syncthreads();   // all sk reads done before red overwrites it
    #pragma unroll
    for (int k = 0; k < 8; ++k) red[lgrp * 128 + oc8 + k] = acc[k];
    __syncthreads();

    if (tid < 128) {
        float m = red[tid];
        #pragma unroll
        for (int g = 1; g < 16; ++g) m = fmaxf(m, red[g * 128 + tid]);
        atomicMax(&pooled[b * OC + tid], __float_as_int(m));
    }
}

// ---------------------------------------------------------------------------
// Kernel C: out[b][t] = pooled[b] . fc1_w[t] + fc1_b[t]   (R6-exact)
// ---------------------------------------------------------------------------
__global__ __launch_bounds__(128) void head(const int* __restrict__ pooled,
                                            const float* __restrict__ fc1w,
                                            const float* __restrict__ fc1b,
                                            float* __restrict__ out) {
    const int tid = threadIdx.x;
    const int b = tid >> 2;
    const int t = tid & 3;
    float acc = fc1b[t];
    #pragma unroll 4
    for (int oc = 0; oc < OC; ++oc)
        acc += __int_as_float(pooled[b * OC + oc]) * fc1w[t * OC + oc];
    out[b * TCO + t] = acc;
}

// ---------------------------------------------------------------------------
// Fallback (ws too small): gather from original f32 layout, atomics path.
// ---------------------------------------------------------------------------
__global__ __launch_bounds__(256) void conv_max_fallback(const int* __restrict__ tokens,
                                                         const float* __restrict__ K,
                                                         int* __restrict__ pooled) {
    const int b   = blockIdx.y;
    const int l0  = blockIdx.x * 64;
    const int tid = threadIdx.x;

    __shared__ int ids[64 + KW - 1];
    if (tid < 64 + KW - 1) {
        const int l = l0 + tid;
        ids[tid] = (l < L_IN) ? tokens[b * L_IN + l] : 0;
    }
    __syncthreads();

    const int oc   = tid & 127;
    const int half = tid >> 7;
    float m = 0.f;
    for (int u = 0; u < 32; ++u) {
        const int li = u * 2 + half;
        const int l  = l0 + li;
        if (l < L_OUT) {
            float s = 0.f;
            #pragma unroll
            for (int w = 0; w < KW; ++w)
                s += K[(size_t)oc * K_ROW + ids[li + w] * KW + w];
            m = fmaxf(m, s);
        }
    }
    atomicMax(&pooled[b * OC + oc], __float_as_int(m));
}

extern "C" void kernel_launch(void* const* d_in, const int* in_sizes, int n_in,
                              void* d_out, int out_size, void* d_ws, size_t ws_size,
                              hipStream_t stream) {
    const int*   tokens = (const int*)d_in[0];
    const float* K      = (const float*)d_in[1];
    const float* fc1w   = (const float*)d_in[2];
    const float* fc1b   = (const float*)d_in[3];
    float*       out    = (float*)d_out;

    const size_t kthBytes    = (size_t)NI * OC * sizeof(__half);  // 38.4 MB
    const size_t pooledBytes = (size_t)NB * OC * sizeof(int);     // 16 KB

    if (ws_size >= kthBytes + pooledBytes) {
        __half* Kth  = (__half*)d_ws;
        int* pooled  = (int*)((char*)d_ws + kthBytes);
        hipMemsetAsync(pooled, 0, pooledBytes, stream);
        transpose_k<<<NI / 48, 256, 0, stream>>>(K, Kth);               // 3125 blocks
        conv_max<<<dim3(NT, NB), 256, 0, stream>>>(tokens, Kth, pooled); // 2560 blocks
        head<<<1, 128, 0, stream>>>(pooled, fc1w, fc1b, out);
    } else {
        int* pooled = (int*)d_ws;
        hipMemsetAsync(pooled, 0, pooledBytes, stream);
        conv_max_fallback<<<dim3((L_OUT + 63) / 64, NB), 256, 0, stream>>>(tokens, K, pooled);
        head<<<1, 128, 0, stream>>>(pooled, fc1w, fc1b, out);
    }
}

// Round 13
// 133.299 us; speedup vs baseline: 1.1880x; 1.1118x over previous
//
#include <hip/hip_runtime.h>
#include <hip/hip_fp16.h>
#include <hip/hip_fp8.h>

#define OC 128
#define V_SZ 30000
#define KW 5
#define L_IN 2560              // 40*64
#define L_OUT (L_IN - KW + 1)  // 2556
#define NB 32
#define TCO 4
#define K_ROW (V_SZ * KW)      // 150000 floats per oc row
#define NI (V_SZ * KW)         // i = v*5+w index space
#define LTILE 32               // conv l-tile
#define NT ((L_OUT + LTILE - 1) / LTILE)   // 80 conv tiles
#define KSCALE 64.0f           // fp8 pre-scale (relu/max are +-homogeneous)
#define KSCALE_INV 0.015625f

// ---------------------------------------------------------------------------
// Kernel A: transpose + fp8-convert  K[oc][i] (f32) -> Kf8[i][oc] (e4m3, x64).
// Read phase R6-EXACT (best measured). Write phase: 8 fp8 bytes/lane packed
// into one 8B store; wave writes 2 rows x 128B contiguous.
// ---------------------------------------------------------------------------
__global__ __launch_bounds__(256) void transpose_k(const float* __restrict__ K,
                                                   unsigned char* __restrict__ Kf8) {
    __shared__ float lds[48 * 132];
    const int i0  = blockIdx.x * 48;
    const int tid = threadIdx.x;

    {
        const int ii4 = (tid & 3) * 4;
        const int ocr = tid >> 2;   // 0..63
        #pragma unroll
        for (int p = 0; p < 3; ++p) {
            #pragma unroll
            for (int r = 0; r < 2; ++r) {
                const int oc = r * 64 + ocr;
                const int ii = p * 16 + ii4;
                const float4 kv = *reinterpret_cast<const float4*>(
                    &K[(size_t)oc * K_ROW + i0 + ii]);
                lds[(ii + 0) * 132 + oc] = kv.x;
                lds[(ii + 1) * 132 + oc] = kv.y;
                lds[(ii + 2) * 132 + oc] = kv.z;
                lds[(ii + 3) * 132 + oc] = kv.w;
            }
        }
    }
    __syncthreads();
    {
        const int oc8 = (tid & 15) * 8;
        #pragma unroll
        for (int p = 0; p < 3; ++p) {
            const int i_loc = p * 16 + (tid >> 4);
            unsigned long long pack = 0ull;
            #pragma unroll
            for (int k = 0; k < 8; ++k) {
                const __hip_fp8_e4m3 f8(lds[i_loc * 132 + oc8 + k] * KSCALE);
                pack |= (unsigned long long)(f8.__x) << (8 * k);
            }
            *reinterpret_cast<unsigned long long*>(
                &Kf8[(size_t)(i0 + i_loc) * OC + oc8]) = pack;
        }
    }
}

// ---------------------------------------------------------------------------
// Kernel B: conv + relu + max-pool from fp8 Kf8 — R6-EXACT structure, half
// the gather bytes (8B/lane row-gathers). f32 accumulate. LDS reduce +
// 128 atomicMax/block epilogue.
// ---------------------------------------------------------------------------
__global__ __launch_bounds__(256) void conv_max(const int* __restrict__ tokens,
                                                const unsigned char* __restrict__ Kf8,
                                                int* __restrict__ pooled) {
    __shared__ int   ids[LTILE + KW - 1];   // 36
    __shared__ float red[16 * 128];
    const int b   = blockIdx.y;
    const int l0  = blockIdx.x * LTILE;
    const int tid = threadIdx.x;

    if (tid < LTILE + KW - 1) {
        const int l = l0 + tid;
        ids[tid] = (l < L_IN) ? tokens[b * L_IN + l] : 0;
    }
    __syncthreads();

    const int lgrp = tid >> 4;        // 0..15
    const int oc8  = (tid & 15) * 8;  // 0..120

    float acc[8];
    #pragma unroll
    for (int k = 0; k < 8; ++k) acc[k] = 0.f;

    #pragma unroll
    for (int u = 0; u < 2; ++u) {
        const int li = u * 16 + lgrp;     // 0..31
        const int l  = l0 + li;
        if (l < L_OUT) {
            float s[8];
            #pragma unroll
            for (int k = 0; k < 8; ++k) s[k] = 0.f;
            #pragma unroll
            for (int w = 0; w < KW; ++w) {
                const int id = ids[li + w];
                const float2 raw = *reinterpret_cast<const float2*>(
                    &Kf8[((size_t)id * KW + w) * OC + oc8]);
                const __hip_fp8_e4m3* f8 =
                    reinterpret_cast<const __hip_fp8_e4m3*>(&raw);
                #pragma unroll
                for (int k = 0; k < 8; ++k) s[k] += (float)f8[k];
            }
            #pragma unroll
            for (int k = 0; k < 8; ++k) acc[k] = fmaxf(acc[k], s[k]);
        }
    }

    #pragma unroll
    for (int k = 0; k < 8; ++k) red[lgrp * 128 + oc8 + k] = acc[k];
    __syncthreads();

    if (tid < 128) {
        float m = red[tid];
        #pragma unroll
        for (int g = 1; g < 16; ++g) m = fmaxf(m, red[g * 128 + tid]);
        atomicMax(&pooled[b * OC + tid], __float_as_int(m));
    }
}

// ---------------------------------------------------------------------------
// Kernel C: out[b][t] = (pooled[b]/KSCALE) . fc1_w[t] + fc1_b[t]
// ---------------------------------------------------------------------------
__global__ __launch_bounds__(128) void head(const int* __restrict__ pooled,
                                            const float* __restrict__ fc1w,
                                            const float* __restrict__ fc1b,
                                            float* __restrict__ out) {
    const int tid = threadIdx.x;
    const int b = tid >> 2;
    const int t = tid & 3;
    float acc = fc1b[t];
    #pragma unroll 4
    for (int oc = 0; oc < OC; ++oc)
        acc += __int_as_float(pooled[b * OC + oc]) * KSCALE_INV * fc1w[t * OC + oc];
    out[b * TCO + t] = acc;
}

// ---------------------------------------------------------------------------
// Fallback (ws too small): gather from original f32 layout, atomics path.
// ---------------------------------------------------------------------------
__global__ __launch_bounds__(256) void conv_max_fallback(const int* __restrict__ tokens,
                                                         const float* __restrict__ K,
                                                         int* __restrict__ pooled) {
    const int b   = blockIdx.y;
    const int l0  = blockIdx.x * 64;
    const int tid = threadIdx.x;

    __shared__ int ids[64 + KW - 1];
    if (tid < 64 + KW - 1) {
        const int l = l0 + tid;
        ids[tid] = (l < L_IN) ? tokens[b * L_IN + l] : 0;
    }
    __syncthreads();

    const int oc   = tid & 127;
    const int half = tid >> 7;
    float m = 0.f;
    for (int u = 0; u < 32; ++u) {
        const int li = u * 2 + half;
        const int l  = l0 + li;
        if (l < L_OUT) {
            float s = 0.f;
            #pragma unroll
            for (int w = 0; w < KW; ++w)
                s += K[(size_t)oc * K_ROW + ids[li + w] * KW + w];
            m = fmaxf(m, s);
        }
    }
    atomicMax(&pooled[b * OC + oc], __float_as_int(m));
}

__global__ __launch_bounds__(128) void head_fallback(const int* __restrict__ pooled,
                                                     const float* __restrict__ fc1w,
                                                     const float* __restrict__ fc1b,
                                                     float* __restrict__ out) {
    const int tid = threadIdx.x;
    const int b = tid >> 2;
    const int t = tid & 3;
    float acc = fc1b[t];
    #pragma unroll 4
    for (int oc = 0; oc < OC; ++oc)
        acc += __int_as_float(pooled[b * OC + oc]) * fc1w[t * OC + oc];
    out[b * TCO + t] = acc;
}

extern "C" void kernel_launch(void* const* d_in, const int* in_sizes, int n_in,
                              void* d_out, int out_size, void* d_ws, size_t ws_size,
                              hipStream_t stream) {
    const int*   tokens = (const int*)d_in[0];
    const float* K      = (const float*)d_in[1];
    const float* fc1w   = (const float*)d_in[2];
    const float* fc1b   = (const float*)d_in[3];
    float*       out    = (float*)d_out;

    const size_t kf8Bytes    = (size_t)NI * OC;                   // 19.2 MB
    const size_t pooledBytes = (size_t)NB * OC * sizeof(int);     // 16 KB

    if (ws_size >= kf8Bytes + pooledBytes) {
        unsigned char* Kf8 = (unsigned char*)d_ws;
        int* pooled = (int*)((char*)d_ws + kf8Bytes);
        hipMemsetAsync(pooled, 0, pooledBytes, stream);
        transpose_k<<<NI / 48, 256, 0, stream>>>(K, Kf8);               // 3125 blocks
        conv_max<<<dim3(NT, NB), 256, 0, stream>>>(tokens, Kf8, pooled); // 2560 blocks
        head<<<1, 128, 0, stream>>>(pooled, fc1w, fc1b, out);
    } else {
        int* pooled = (int*)d_ws;
        hipMemsetAsync(pooled, 0, pooledBytes, stream);
        conv_max_fallback<<<dim3((L_OUT + 63) / 64, NB), 256, 0, stream>>>(tokens, K, pooled);
        head_fallback<<<1, 128, 0, stream>>>(pooled, fc1w, fc1b, out);
    }
}